// Round 3
// baseline (55.575 us; speedup 1.0000x reference)
//
#include <hip/hip_runtime.h>

// cov = inv(tridiag(prec)) for a fixed 32x32 symmetric tridiagonal matrix,
// broadcast to 65536 copies. Output = 256 MiB fp32 -> pure store-BW bound.
// Harness fillBuffer shows ~7.0 TB/s pure-write ceiling on this chip; target
// ~38-39 us. Changes vs R1 (45.7 us / 5.88 TB/s):
//   - copies-per-block compile-time (32) -> full unroll, 32 back-to-back
//     global_store_dwordx4 per thread, deep store ILP.
//   - non-temporal stores via native ext_vector_type (HIP float4 is a class
//     type the builtin rejects -- R2 compile fix).

#define GN 32
#define GBATCH 65536
#define GBLOCKS 2048
#define GCOPIES (GBATCH / GBLOCKS)   // 32 copies of 4 KiB per block

typedef float f32x4 __attribute__((ext_vector_type(4)));

__global__ __launch_bounds__(256) void GGMInvPrecToCovMatLayer_83382495085302_kernel(
    const float* __restrict__ nz,   // 63 vals: [0..31]=diag, [32..62]=off-diag (i+1,i)
    float* __restrict__ out)        // [BATCH, 32, 32] fp32
{
    __shared__ float cov[GN * GN];  // 4 KiB: the 32x32 inverse, row-major
    const int tid = threadIdx.x;

    // --- Step 1: lanes 0..31 each solve A x = e_j (Thomas algorithm), fully
    // unrolled so all per-thread arrays stay in registers with static indices.
    if (tid < GN) {
        const int j = tid;

        float d[GN], e[GN - 1];
        #pragma unroll
        for (int i = 0; i < GN; ++i)     d[i] = nz[i];
        #pragma unroll
        for (int i = 0; i < GN - 1; ++i) e[i] = nz[GN + i];

        float w[GN], g[GN];
        {
            const float inv0 = 1.0f / d[0];
            w[0] = e[0] * inv0;
            g[0] = (j == 0 ? 1.0f : 0.0f) * inv0;
        }
        #pragma unroll
        for (int i = 1; i < GN; ++i) {
            const float a = e[i - 1];                 // sub-diagonal
            const float m = 1.0f / (d[i] - a * w[i - 1]);
            w[i] = (i < GN - 1 ? e[i] : 0.0f) * m;    // super-diagonal (symmetric)
            g[i] = ((i == j ? 1.0f : 0.0f) - a * g[i - 1]) * m;
        }
        // Back-substitution; x is column j of inv(A) (== row j, symmetric).
        float x = g[GN - 1];
        cov[(GN - 1) * GN + j] = x;
        #pragma unroll
        for (int i = GN - 2; i >= 0; --i) {
            x = g[i] - w[i] * x;
            cov[i * GN + j] = x;
        }
    }
    __syncthreads();

    // --- Step 2: broadcast. Each thread owns one 16B chunk of the 4 KiB
    // tile; each unrolled iteration stores one full contiguous 4 KiB copy
    // (256 lanes x 16B coalesced). Non-temporal: write-once 256 MiB stream
    // (8x aggregate L2), skip cache allocation. Block writes 128 KiB contig.
    const f32x4 v = reinterpret_cast<const f32x4*>(cov)[tid];
    f32x4* __restrict__ out4 = reinterpret_cast<f32x4*>(out)
                             + (size_t)blockIdx.x * (GCOPIES * GN * GN / 4) + tid;
    #pragma unroll
    for (int k = 0; k < GCOPIES; ++k) {
        __builtin_nontemporal_store(v, out4 + (size_t)k * (GN * GN / 4));
    }
}

extern "C" void kernel_launch(void* const* d_in, const int* in_sizes, int n_in,
                              void* d_out, int out_size, void* d_ws, size_t ws_size,
                              hipStream_t stream) {
    // d_in[0] = inputs (unused by reference output), d_in[1] = non_zero_vals,
    // d_in[2] = rows, d_in[3] = cols (layout fixed by setup_inputs).
    const float* nz = (const float*)d_in[1];
    float* out = (float*)d_out;

    GGMInvPrecToCovMatLayer_83382495085302_kernel<<<GBLOCKS, 256, 0, stream>>>(nz, out);
}

// Round 4
// 45.600 us; speedup vs baseline: 1.2188x; 1.2188x over previous
//
#include <hip/hip_runtime.h>

// cov = inv(tridiag(prec)) for a fixed 32x32 symmetric tridiagonal matrix,
// broadcast to 65536 copies. Output = 256 MiB fp32 -> pure store-BW bound.
// History: R1 (runtime loop, plain stores) = 45.7 us (5.88 TB/s).
//          R3 (unrolled + nontemporal)     = 55.6 us  -> nt HURTS on gfx950
//              (bypasses L2 write aggregation; fillBuffer hits 7.0 TB/s
//               through the normal write-back path).
// R4: revert nt, keep compile-time unroll (32 back-to-back dwordx4 stores).

#define GN 32
#define GBATCH 65536
#define GBLOCKS 2048
#define GCOPIES (GBATCH / GBLOCKS)   // 32 copies of 4 KiB per block

typedef float f32x4 __attribute__((ext_vector_type(4)));

__global__ __launch_bounds__(256) void GGMInvPrecToCovMatLayer_83382495085302_kernel(
    const float* __restrict__ nz,   // 63 vals: [0..31]=diag, [32..62]=off-diag (i+1,i)
    float* __restrict__ out)        // [BATCH, 32, 32] fp32
{
    __shared__ float cov[GN * GN];  // 4 KiB: the 32x32 inverse, row-major
    const int tid = threadIdx.x;

    // --- Step 1: lanes 0..31 each solve A x = e_j (Thomas algorithm), fully
    // unrolled so all per-thread arrays stay in registers with static indices.
    if (tid < GN) {
        const int j = tid;

        float d[GN], e[GN - 1];
        #pragma unroll
        for (int i = 0; i < GN; ++i)     d[i] = nz[i];
        #pragma unroll
        for (int i = 0; i < GN - 1; ++i) e[i] = nz[GN + i];

        float w[GN], g[GN];
        {
            const float inv0 = 1.0f / d[0];
            w[0] = e[0] * inv0;
            g[0] = (j == 0 ? 1.0f : 0.0f) * inv0;
        }
        #pragma unroll
        for (int i = 1; i < GN; ++i) {
            const float a = e[i - 1];                 // sub-diagonal
            const float m = 1.0f / (d[i] - a * w[i - 1]);
            w[i] = (i < GN - 1 ? e[i] : 0.0f) * m;    // super-diagonal (symmetric)
            g[i] = ((i == j ? 1.0f : 0.0f) - a * g[i - 1]) * m;
        }
        // Back-substitution; x is column j of inv(A) (== row j, symmetric).
        float x = g[GN - 1];
        cov[(GN - 1) * GN + j] = x;
        #pragma unroll
        for (int i = GN - 2; i >= 0; --i) {
            x = g[i] - w[i] * x;
            cov[i * GN + j] = x;
        }
    }
    __syncthreads();

    // --- Step 2: broadcast. Each thread owns one 16B chunk of the 4 KiB
    // tile; each unrolled iteration stores one full contiguous 4 KiB copy
    // (256 lanes x 16B coalesced). Plain write-back stores: L2 aggregates
    // full lines; nt measured 10 us slower (R3). Block writes 128 KiB contig.
    const f32x4 v = reinterpret_cast<const f32x4*>(cov)[tid];
    f32x4* __restrict__ out4 = reinterpret_cast<f32x4*>(out)
                             + (size_t)blockIdx.x * (GCOPIES * GN * GN / 4) + tid;
    #pragma unroll
    for (int k = 0; k < GCOPIES; ++k) {
        out4[(size_t)k * (GN * GN / 4)] = v;
    }
}

extern "C" void kernel_launch(void* const* d_in, const int* in_sizes, int n_in,
                              void* d_out, int out_size, void* d_ws, size_t ws_size,
                              hipStream_t stream) {
    // d_in[0] = inputs (unused by reference output), d_in[1] = non_zero_vals,
    // d_in[2] = rows, d_in[3] = cols (layout fixed by setup_inputs).
    const float* nz = (const float*)d_in[1];
    float* out = (float*)d_out;

    GGMInvPrecToCovMatLayer_83382495085302_kernel<<<GBLOCKS, 256, 0, stream>>>(nz, out);
}

// Round 5
// 45.556 us; speedup vs baseline: 1.2199x; 1.0010x over previous
//
#include <hip/hip_runtime.h>

// cov = inv(tridiag(prec)) for a fixed 32x32 symmetric tridiagonal matrix,
// broadcast to 65536 copies. Output = 256 MiB fp32 -> pure store-BW bound.
// History: R1 (2048 blk, runtime loop)   = 45.7 us (5.88 TB/s)
//          R3 (2048 blk, unroll + nt)    = 55.6 us  -> nt HURTS on gfx950
//          R4 (2048 blk, unroll only)    = 45.6 us  -> unroll neutral
// fillBufferAligned reference on same chip: 6.7-7.1 TB/s at ~10.6% occupancy
// (~3.4 waves/CU, few LONG linear streams). R5 theory: our 32 waves/CU x
// 8 blocks/CU = ~2048 interleaved 1KiB store streams chip-wide kills HBM
// row-buffer locality. Mimic fill: 256 blocks (1/CU, 4 waves), each CU
// writes ONE contiguous 1 MiB region sequentially.

#define GN 32
#define GBATCH 65536
#define GBLOCKS 256
#define GCOPIES (GBATCH / GBLOCKS)   // 256 copies of 4 KiB per block

typedef float f32x4 __attribute__((ext_vector_type(4)));

__global__ __launch_bounds__(256) void GGMInvPrecToCovMatLayer_83382495085302_kernel(
    const float* __restrict__ nz,   // 63 vals: [0..31]=diag, [32..62]=off-diag (i+1,i)
    float* __restrict__ out)        // [BATCH, 32, 32] fp32
{
    __shared__ float cov[GN * GN];  // 4 KiB: the 32x32 inverse, row-major
    const int tid = threadIdx.x;

    // --- Step 1: lanes 0..31 each solve A x = e_j (Thomas algorithm), fully
    // unrolled so all per-thread arrays stay in registers with static indices.
    if (tid < GN) {
        const int j = tid;

        float d[GN], e[GN - 1];
        #pragma unroll
        for (int i = 0; i < GN; ++i)     d[i] = nz[i];
        #pragma unroll
        for (int i = 0; i < GN - 1; ++i) e[i] = nz[GN + i];

        float w[GN], g[GN];
        {
            const float inv0 = 1.0f / d[0];
            w[0] = e[0] * inv0;
            g[0] = (j == 0 ? 1.0f : 0.0f) * inv0;
        }
        #pragma unroll
        for (int i = 1; i < GN; ++i) {
            const float a = e[i - 1];                 // sub-diagonal
            const float m = 1.0f / (d[i] - a * w[i - 1]);
            w[i] = (i < GN - 1 ? e[i] : 0.0f) * m;    // super-diagonal (symmetric)
            g[i] = ((i == j ? 1.0f : 0.0f) - a * g[i - 1]) * m;
        }
        // Back-substitution; x is column j of inv(A) (== row j, symmetric).
        float x = g[GN - 1];
        cov[(GN - 1) * GN + j] = x;
        #pragma unroll
        for (int i = GN - 2; i >= 0; --i) {
            x = g[i] - w[i] * x;
            cov[i * GN + j] = x;
        }
    }
    __syncthreads();

    // --- Step 2: broadcast. Each thread owns one 16B chunk of the 4 KiB
    // tile; each iteration stores one full contiguous 4 KiB copy (256 lanes
    // x 16B coalesced). Block (= CU) streams one contiguous 1 MiB region.
    // Plain write-back stores (nt measured -18% in R3).
    const f32x4 v = reinterpret_cast<const f32x4*>(cov)[tid];
    f32x4* __restrict__ out4 = reinterpret_cast<f32x4*>(out)
                             + (size_t)blockIdx.x * (GCOPIES * GN * GN / 4) + tid;
    #pragma unroll 4
    for (int k = 0; k < GCOPIES; ++k) {
        out4[(size_t)k * (GN * GN / 4)] = v;
    }
}

extern "C" void kernel_launch(void* const* d_in, const int* in_sizes, int n_in,
                              void* d_out, int out_size, void* d_ws, size_t ws_size,
                              hipStream_t stream) {
    // d_in[0] = inputs (unused by reference output), d_in[1] = non_zero_vals,
    // d_in[2] = rows, d_in[3] = cols (layout fixed by setup_inputs).
    const float* nz = (const float*)d_in[1];
    float* out = (float*)d_out;

    GGMInvPrecToCovMatLayer_83382495085302_kernel<<<GBLOCKS, 256, 0, stream>>>(nz, out);
}